// Round 10
// baseline (820.962 us; speedup 1.0000x reference)
//
#include <hip/hip_runtime.h>
#include <hip/hip_bf16.h>

#define DEV static __device__ __forceinline__

typedef __attribute__((ext_vector_type(8))) _Float16 half8;   // A/B frag: 8 fp16 = 4 VGPR
typedef __attribute__((ext_vector_type(2))) _Float16 half2v;  // pkrtz result
typedef __attribute__((ext_vector_type(4))) float f32x4;      // C/D frag

constexpr int Bc = 4, Tc = 2048, Dc = 2048, Hc = 16;          // HD = 128

DEV ushort f2h(float f) { _Float16 h = (_Float16)f; return __builtin_bit_cast(ushort, h); }
DEV float  h2f(ushort u) { return (float)__builtin_bit_cast(_Float16, u); }
DEV uint pk2h(float a, float b) {
  return __builtin_bit_cast(uint, __builtin_amdgcn_cvt_pkrtz(a, b));
}

DEV f32x4 MFMA(half8 a, half8 b, f32x4 c) {
  return __builtin_amdgcn_mfma_f32_16x16x32_f16(a, b, c, 0, 0, 0);
}

DEV void async_cp16(void* lds, const void* g) {
  __builtin_amdgcn_global_load_lds((const __attribute__((address_space(1))) void*)g,
                                   (__attribute__((address_space(3))) void*)lds,
                                   16, 0, 0);
}

// ---------------- f32 -> fp16 convert ----------------
__global__ __launch_bounds__(256) void cvt(const float* __restrict__ in,
                                           ushort* __restrict__ out, int n4) {
  const int i = blockIdx.x * 256 + threadIdx.x;
  if (i >= n4) return;
  const float4 v = ((const float4*)in)[i];
  ushort4 o;
  o.x = f2h(v.x); o.y = f2h(v.y); o.z = f2h(v.z); o.w = f2h(v.w);
  ((ushort4*)out)[i] = o;
}

// ---------------- GEMM 256x256, BK=32, 4-slot ring, fine-phase pipeline ----
template <typename OutT>
__global__ __launch_bounds__(512, 2) void gemm256(const ushort* __restrict__ A,
                                                  const ushort* __restrict__ Bw,
                                                  OutT* __restrict__ C) {
  __shared__ ushort As[4][256 * 32];
  __shared__ ushort Bs[4][256 * 32];
  const int tid = threadIdx.x;                 // 0..511
  const int lane = tid & 63, wid = tid >> 6;   // 8 waves
  const int g = lane >> 4, q16 = lane & 15;
  const int wm = wid >> 2, wn = wid & 3;       // 2M x 4N

  const int flat = (int)blockIdx.x;            // 0..255
  const int xcd = flat & 7, idx = flat >> 3;   // idx 0..31
  const int bm = xcd * 4 + (idx & 3);          // 4 bm-panels per XCD
  const int bn = idx >> 2;                     // 0..7
  const ushort* Ab = A + (size_t)bm * 256 * Dc;
  const ushort* Bb = Bw + (size_t)bn * 256 * Dc;

#define STAGE1(KT, BUF, PH) do {                                               \
    const int pass_ = (PH) & 1;                                                \
    const int c_ = pass_ * 512 + tid;                                          \
    const int row_ = c_ >> 2, gl_ = c_ & 3;                                    \
    const int col_ = (KT) * 32 + ((gl_ ^ ((row_ >> 1) & 3)) << 3);             \
    if ((PH) < 2)                                                              \
      async_cp16(&As[BUF][(pass_ * 512 + wid * 64) * 8],                       \
                 Ab + (size_t)row_ * Dc + col_);                               \
    else                                                                       \
      async_cp16(&Bs[BUF][(pass_ * 512 + wid * 64) * 8],                       \
                 Bb + (size_t)row_ * Dc + col_);                               \
  } while (0)

  f32x4 acc[8][4] = {};

  for (int tt = 0; tt < 3; ++tt) {
    STAGE1(tt, tt, 0); STAGE1(tt, tt, 1);
    STAGE1(tt, tt, 2); STAGE1(tt, tt, 3);
  }
  asm volatile("s_waitcnt vmcnt(0)" ::: "memory");
  __builtin_amdgcn_s_barrier();
  __builtin_amdgcn_sched_barrier(0);

  const int sgz = (g ^ ((q16 >> 1) & 3)) << 3;

#define PHASE(AA, BB, RDA, RDB, PH) do {                                       \
    if (RDA) {                                                                 \
      _Pragma("unroll") for (int mf_ = 0; mf_ < 4; ++mf_) {                    \
        const int r_ = wm * 128 + (AA) * 64 + mf_ * 16 + q16;                  \
        af[mf_] = *(const half8*)&Asb[r_ * 32 + sgz];                          \
      }                                                                        \
    }                                                                          \
    if (RDB) {                                                                 \
      _Pragma("unroll") for (int nf_ = 0; nf_ < 2; ++nf_) {                    \
        const int r_ = wn * 64 + (BB) * 32 + nf_ * 16 + q16;                   \
        bf[nf_] = *(const half8*)&Bsb[r_ * 32 + sgz];                          \
      }                                                                        \
    }                                                                          \
    if (st) STAGE1(t + 3, sb, PH);                                             \
    asm volatile("s_waitcnt vmcnt(8)" ::: "memory");                           \
    __builtin_amdgcn_s_barrier();                                              \
    __builtin_amdgcn_sched_barrier(0);                                         \
    __builtin_amdgcn_s_setprio(1);                                             \
    _Pragma("unroll") for (int mf_ = 0; mf_ < 4; ++mf_)                        \
      _Pragma("unroll") for (int nf_ = 0; nf_ < 2; ++nf_)                      \
        acc[(AA) * 4 + mf_][(BB) * 2 + nf_] =                                  \
            MFMA(af[mf_], bf[nf_], acc[(AA) * 4 + mf_][(BB) * 2 + nf_]);       \
    __builtin_amdgcn_s_setprio(0);                                             \
  } while (0)

#pragma unroll 1
  for (int t = 0; t < 64; ++t) {
    const int rb = t & 3;
    const int sb = (t + 3) & 3;
    const bool st = (t + 3) < 64;
    const ushort* Asb = As[rb];
    const ushort* Bsb = Bs[rb];
    half8 af[4], bf[2];
    PHASE(0, 0, 1, 1, 0);
    PHASE(0, 1, 0, 1, 1);
    PHASE(1, 1, 1, 0, 2);
    PHASE(1, 0, 0, 1, 3);
  }
#undef PHASE
#undef STAGE1

  const int m00 = bm * 256 + wm * 128 + g * 4;
  const int n0 = bn * 256 + wn * 64 + q16;
#pragma unroll
  for (int mf = 0; mf < 8; ++mf)
#pragma unroll
    for (int nf = 0; nf < 4; ++nf) {
      const int m0 = m00 + mf * 16;
      const int n = n0 + nf * 16;
#pragma unroll
      for (int r = 0; r < 4; ++r) {
        const float v = acc[mf][nf][r];
        if constexpr (sizeof(OutT) == 2)
          C[(size_t)(m0 + r) * Dc + n] = (OutT)f2h(v);
        else
          C[(size_t)(m0 + r) * Dc + n] = (OutT)v;
      }
    }
}

// ---------------- RoPE in-place on [B,T,H,128] fp16 ----------------
__global__ __launch_bounds__(256) void rope(ushort* __restrict__ X,
                                            const float* __restrict__ cs,
                                            const float* __restrict__ sn) {
  const int tid = blockIdx.x * 256 + threadIdx.x;
  const int row = tid >> 4;
  const int jq = (tid & 15) << 2;
  const int t = (row >> 4) & (Tc - 1);
  ushort* base = X + (size_t)row * 128;
  const ushort4 lo = *(const ushort4*)(base + jq);
  const ushort4 hi = *(const ushort4*)(base + 64 + jq);
  const float4 c4 = *(const float4*)(cs + t * 128 + jq);
  const float4 s4 = *(const float4*)(sn + t * 128 + jq);
  const float xl[4] = {h2f(lo.x), h2f(lo.y), h2f(lo.z), h2f(lo.w)};
  const float xh[4] = {h2f(hi.x), h2f(hi.y), h2f(hi.z), h2f(hi.w)};
  const float cc[4] = {c4.x, c4.y, c4.z, c4.w};
  const float ss[4] = {s4.x, s4.y, s4.z, s4.w};
  ushort4 olo, ohi;
  ushort* po = (ushort*)&olo;
  ushort* ph = (ushort*)&ohi;
#pragma unroll
  for (int k = 0; k < 4; ++k) {
    po[k] = f2h(xl[k] * cc[k] - xh[k] * ss[k]);
    ph[k] = f2h(xh[k] * cc[k] + xl[k] * ss[k]);
  }
  *(ushort4*)(base + jq) = olo;
  *(ushort4*)(base + 64 + jq) = ohi;
}

// ---------------- causal flash attention (high-occupancy) ----------------
// 1024 blocks x 256 threads (4 waves x 2 chains x 16 rows = 128-row q-tile).
// KVBLK=32 -> LDS 32KB -> 4 blocks/CU co-resident (16 waves/CU, 4/SIMD);
// whole grid resident. Tile permutation {15-r, r, 8+r, 7-r} makes each CU's
// 4 blocks sum to uniform 136 kv-iters (round-robin dispatch). Head-major XCD
// swizzle for K/V L2 locality. In-register P redistribution (3 shfl-pairs per
// chain); pkrtz packing; T13 defer-max; T14 V-stage split.
__global__ __launch_bounds__(256, 4) void attn(const ushort* __restrict__ Q,
                                               const ushort* __restrict__ K,
                                               const ushort* __restrict__ V,
                                               ushort* __restrict__ O) {
  __shared__ ushort Ks[2][32 * 128];   // [kv][d], granule ^= kv&7
  __shared__ ushort Vt[2][128 * 32];   // [d][kv], granule ^= d&3

  const int tid = threadIdx.x;         // 0..255
  const int lane = tid & 63, wid = tid >> 6;   // wid 0..3
  const int g = lane >> 4, q16 = lane & 15;

  const int flat = (int)blockIdx.x;    // 0..1023
  const int xcd = flat & 7, idx = flat >> 3;          // idx 0..127
  const int bh = xcd + 8 * (idx & 7);                 // head-slot 0..63
  const int rank = idx >> 3;                          // 0..15
  const int rk = rank >> 2, rb2 = rank & 3;
  const int qt = (rk == 0) ? (15 - rb2)
               : (rk == 1) ? rb2
               : (rk == 2) ? (8 + rb2) : (7 - rb2);   // per-CU sums uniform

  const int b = bh >> 4, h = bh & 15;
  const size_t headbase = ((size_t)b * Tc * Hc + h) * 128;  // t-stride = 2048
  const float SCL2 = 0.12751743f;      // log2(e)/sqrt(128)

  const int qrow = qt * 128 + wid * 32;     // wave owns rows qrow..qrow+31
  const int nt = qt * 4 + 4;

  const int vdc = wid * 4 + (lane & 3);     // 0..15: d = vdc*8..+7
  const int vkvp = lane >> 2;               // 0..15: kv pair

  uint4 vreg[2];

#define ISSUEK(KT, BUF) do {                                                   \
    const ushort* Kb_ = K + headbase + (size_t)(KT) * 32 * Dc;                 \
    _Pragma("unroll") for (int i_ = 0; i_ < 2; ++i_) {                         \
      const int c_ = i_ * 256 + tid;                                           \
      const int kv_ = c_ >> 4, gl_ = c_ & 15;                                  \
      async_cp16(&Ks[BUF][(i_ * 256 + wid * 64) * 8],                          \
                 Kb_ + (size_t)kv_ * Dc + ((gl_ ^ (kv_ & 7)) << 3));           \
    }                                                                          \
  } while (0)

#define LOADV(KT) do {                                                         \
    const ushort* p0_ = V + headbase + (size_t)((KT) * 32 + 2 * vkvp) * Dc +   \
                        vdc * 8;                                               \
    vreg[0] = *(const uint4*)p0_;                                              \
    vreg[1] = *(const uint4*)(p0_ + Dc);                                       \
  } while (0)

#define WRITEV(BUF) do {                                                       \
    const ushort* e0_ = (const ushort*)&vreg[0];                               \
    const ushort* e1_ = (const ushort*)&vreg[1];                               \
    _Pragma("unroll") for (int j_ = 0; j_ < 8; ++j_) {                         \
      const int d_ = vdc * 8 + j_;                                             \
      const unsigned w_ = (unsigned)e0_[j_] | ((unsigned)e1_[j_] << 16);       \
      *(unsigned*)&Vt[BUF][(d_ * 32 + 2 * vkvp) ^ ((d_ & 3) << 3)] = w_;       \
    }                                                                          \
  } while (0)

  // Q fragments, 2 chains (B-op: col=q=lane&15, k=d=g*8+j)
  half8 qreg[2][4];
#pragma unroll
  for (int qf = 0; qf < 2; ++qf)
#pragma unroll
    for (int ds = 0; ds < 4; ++ds)
      qreg[qf][ds] = *(const half8*)(Q + headbase +
                     (size_t)(qrow + qf * 16 + q16) * Dc + ds * 32 + g * 8);

  f32x4 oacc[2][8] = {};               // O^T frags: row=d (g*4+r), col=q
  float m_[2] = {-1e30f, -1e30f};
  float l_[2] = {0.f, 0.f};            // per-lane partials (own 8 kv/iter)

  ISSUEK(0, 0);
  LOADV(0);
  WRITEV(0);                           // compiler waits vmcnt for vreg here

#pragma unroll 1
  for (int kt = 0; kt < nt; ++kt) {
    const int cur = kt & 1;
    const int kv0 = kt * 32;
    asm volatile("s_waitcnt vmcnt(0) lgkmcnt(0)" ::: "memory");
    __builtin_amdgcn_s_barrier();
    __builtin_amdgcn_sched_barrier(0);
    if (kt + 1 < nt) {
      ISSUEK(kt + 1, cur ^ 1);
      LOADV(kt + 1);
    }

    if (kv0 <= qrow + 31) {            // wave-uniform
      const ushort* Ksb = Ks[cur];
      const ushort* Vtb = Vt[cur];
      // S^T = K Q^T, both chains share kf
      f32x4 s[2][2] = {};
      __builtin_amdgcn_s_setprio(1);
#pragma unroll
      for (int ds = 0; ds < 4; ++ds) {
        half8 kf[2];
#pragma unroll
        for (int kvf = 0; kvf < 2; ++kvf) {
          const int kv = kvf * 16 + q16;
          kf[kvf] = *(const half8*)&Ksb[(kv * 128 + ds * 32 + g * 8) ^ ((kv & 7) << 3)];
        }
#pragma unroll
        for (int kvf = 0; kvf < 2; ++kvf)
#pragma unroll
          for (int qf = 0; qf < 2; ++qf)
            s[qf][kvf] = MFMA(kf[kvf], qreg[qf][ds], s[qf][kvf]);
      }
      __builtin_amdgcn_s_setprio(0);
      // causal mask + running max; mask only on diagonal tiles
      float pmax[2] = {-1e30f, -1e30f};
      if (kv0 + 31 > qrow) {
#pragma unroll
        for (int qf = 0; qf < 2; ++qf) {
          const int qg = qrow + qf * 16 + q16;
#pragma unroll
          for (int kvf = 0; kvf < 2; ++kvf)
#pragma unroll
            for (int r = 0; r < 4; ++r) {
              float v = s[qf][kvf][r];
              if ((kv0 + kvf * 16 + g * 4 + r) > qg) v = -1e30f;
              s[qf][kvf][r] = v;
              pmax[qf] = fmaxf(pmax[qf], v);
            }
        }
      } else {
#pragma unroll
        for (int qf = 0; qf < 2; ++qf)
#pragma unroll
          for (int kvf = 0; kvf < 2; ++kvf)
#pragma unroll
            for (int r = 0; r < 4; ++r)
              pmax[qf] = fmaxf(pmax[qf], s[qf][kvf][r]);
      }
#pragma unroll
      for (int qf = 0; qf < 2; ++qf) {
        pmax[qf] = fmaxf(pmax[qf], __shfl_xor(pmax[qf], 16));
        pmax[qf] = fmaxf(pmax[qf], __shfl_xor(pmax[qf], 32));
      }
      // T13 defer-max
      if (!__all((pmax[0] <= m_[0] + 16.f) & (pmax[1] <= m_[1] + 16.f))) {
#pragma unroll
        for (int qf = 0; qf < 2; ++qf) {
          const float mn2 = fmaxf(m_[qf], pmax[qf]);
          const float alpha = __builtin_exp2f((m_[qf] - mn2) * SCL2);
          m_[qf] = mn2;
          l_[qf] *= alpha;
#pragma unroll
          for (int df = 0; df < 8; ++df)
            oacc[qf][df] *= alpha;
        }
      }
      // exp + pkrtz pack: w[qf][kvf][i], kv = kvf*16+g*4+2i
      uint w[2][2][2];
#pragma unroll
      for (int qf = 0; qf < 2; ++qf) {
        const float mn = m_[qf];
        float lsum = 0.f;
#pragma unroll
        for (int kvf = 0; kvf < 2; ++kvf) {
          const float p0 = __builtin_exp2f((s[qf][kvf][0] - mn) * SCL2);
          const float p1 = __builtin_exp2f((s[qf][kvf][1] - mn) * SCL2);
          const float p2 = __builtin_exp2f((s[qf][kvf][2] - mn) * SCL2);
          const float p3 = __builtin_exp2f((s[qf][kvf][3] - mn) * SCL2);
          lsum += (p0 + p1) + (p2 + p3);
          w[qf][kvf][0] = pk2h(p0, p1);
          w[qf][kvf][1] = pk2h(p2, p3);
        }
        l_[qf] += lsum;
      }
      // In-register P redistribution (K=32): target dword m: kv = g*8+2m from
      // source lane g_s=(2g+(m>>1))&3, reg w[g>>1][m&1]. 3 shfl-pairs/chain:
      //  X16: lane1->0 (w0), lane2->3 (w1);  X32: lane3->1 (w0), lane0->2 (w1)
      //  X48: lane2->1 (w0), lane1->2 (w1)
      const bool ghi = g >= 2;
      const bool godd = (g & 1) != 0;
      half8 pb[2];
#pragma unroll
      for (int qf = 0; qf < 2; ++qf) {
        const uint* w0 = w[qf][0];
        const uint* w1 = w[qf][1];
        uint R16[2], R32[2], R48[2];
#pragma unroll
        for (int i = 0; i < 2; ++i) {
          const uint S16 = (g == 1) ? w0[i] : w1[i];
          const uint S32 = (g == 3) ? w0[i] : w1[i];
          const uint S48 = (g == 2) ? w0[i] : w1[i];
          R16[i] = __shfl_xor(S16, 16);
          R32[i] = __shfl_xor(S32, 32);
          R48[i] = __shfl_xor(S48, 48);
        }
        uint4 t;
        t.x = !ghi ? (godd ? R48[0] : w0[0]) : (godd ? R16[0] : R32[0]);
        t.y = !ghi ? (godd ? R48[1] : w0[1]) : (godd ? R16[1] : R32[1]);
        t.z = !ghi ? (godd ? R32[0] : R16[0]) : (godd ? w1[0] : R48[0]);
        t.w = !ghi ? (godd ? R32[1] : R16[1]) : (godd ? w1[1] : R48[1]);
        pb[qf] = __builtin_bit_cast(half8, t);
      }
      // O^T += V^T P^T, chains share vf
      __builtin_amdgcn_s_setprio(1);
#pragma unroll
      for (int df = 0; df < 8; ++df) {
        const int d = df * 16 + q16;
        const half8 vf = *(const half8*)&Vtb[(d * 32 + g * 8) ^ ((d & 3) << 3)];
#pragma unroll
        for (int qf = 0; qf < 2; ++qf)
          oacc[qf][df] = MFMA(vf, pb[qf], oacc[qf][df]);
      }
      __builtin_amdgcn_s_setprio(0);
    }

    if (kt + 1 < nt) WRITEV(cur ^ 1);  // vreg vmcnt wait lands here, hidden
  }

  // epilogue: reduce per-lane l partials, store O fp16
#pragma unroll
  for (int qf = 0; qf < 2; ++qf) {
    float l = l_[qf];
    l += __shfl_xor(l, 16);
    l += __shfl_xor(l, 32);
    const float inv = 1.0f / l;
    const int t = qrow + qf * 16 + q16;
#pragma unroll
    for (int df = 0; df < 8; ++df) {
      const f32x4 v = oacc[qf][df];
      ushort4 o;
      o.x = f2h(v[0] * inv); o.y = f2h(v[1] * inv);
      o.z = f2h(v[2] * inv); o.w = f2h(v[3] * inv);
      *(ushort4*)(O + headbase + (size_t)t * Dc + df * 16 + g * 4) = o;
    }
  }
#undef ISSUEK
#undef LOADV
#undef WRITEV
}

extern "C" void kernel_launch(void* const* d_in, const int* in_sizes, int n_in,
                              void* d_out, int out_size, void* d_ws, size_t ws_size,
                              hipStream_t stream) {
  (void)in_sizes; (void)n_in; (void)out_size; (void)ws_size;
  const float* x  = (const float*)d_in[0];
  const float* cs = (const float*)d_in[1];
  const float* sn = (const float*)d_in[2];
  // d_in[3] = mask (unused: causal handled analytically)
  const float* Wq = (const float*)d_in[4];
  const float* Wk = (const float*)d_in[5];
  const float* Wv = (const float*)d_in[6];
  const float* Wo = (const float*)d_in[7];
  float* out = (float*)d_out;

  char* ws = (char*)d_ws;
  const size_t MB = 1024 * 1024;
  ushort* xb  = (ushort*)(ws);            // 32MB x fp16; reused as attn output O
  ushort* wqb = (ushort*)(ws + 32 * MB);
  ushort* wkb = (ushort*)(ws + 40 * MB);
  ushort* wvb = (ushort*)(ws + 48 * MB);
  ushort* wob = (ushort*)(ws + 56 * MB);
  ushort* Qr  = (ushort*)(ws + 64 * MB);  // 32MB each, [B,T,H,128] fp16
  ushort* Kr  = (ushort*)(ws + 96 * MB);
  ushort* Vr  = (ushort*)(ws + 128 * MB); // end: 160MB

  cvt<<<16384, 256, 0, stream>>>(x, xb, 4194304);
  cvt<<<4096, 256, 0, stream>>>(Wq, wqb, 1048576);
  cvt<<<4096, 256, 0, stream>>>(Wk, wkb, 1048576);
  cvt<<<4096, 256, 0, stream>>>(Wv, wvb, 1048576);
  cvt<<<4096, 256, 0, stream>>>(Wo, wob, 1048576);

  gemm256<ushort><<<256, 512, 0, stream>>>(xb, wqb, Qr);
  gemm256<ushort><<<256, 512, 0, stream>>>(xb, wkb, Kr);
  gemm256<ushort><<<256, 512, 0, stream>>>(xb, wvb, Vr);

  rope<<<8192, 256, 0, stream>>>(Qr, cs, sn);
  rope<<<8192, 256, 0, stream>>>(Kr, cs, sn);

  attn<<<1024, 256, 0, stream>>>(Qr, Kr, Vr, xb);

  gemm256<float><<<256, 512, 0, stream>>>(xb, wob, out);
}

// Round 11
// 478.193 us; speedup vs baseline: 1.7168x; 1.7168x over previous
//
#include <hip/hip_runtime.h>
#include <hip/hip_bf16.h>

#define DEV static __device__ __forceinline__

typedef __attribute__((ext_vector_type(8))) _Float16 half8;   // A/B frag: 8 fp16 = 4 VGPR
typedef __attribute__((ext_vector_type(4))) float f32x4;      // C/D frag

constexpr int Bc = 4, Tc = 2048, Dc = 2048, Hc = 16;          // HD = 128

DEV ushort f2h(float f) { _Float16 h = (_Float16)f; return __builtin_bit_cast(ushort, h); }
DEV float  h2f(ushort u) { return (float)__builtin_bit_cast(_Float16, u); }

DEV f32x4 MFMA(half8 a, half8 b, f32x4 c) {
  return __builtin_amdgcn_mfma_f32_16x16x32_f16(a, b, c, 0, 0, 0);
}

DEV void async_cp16(void* lds, const void* g) {
  __builtin_amdgcn_global_load_lds((const __attribute__((address_space(1))) void*)g,
                                   (__attribute__((address_space(3))) void*)lds,
                                   16, 0, 0);
}

// ---------------- f32 -> fp16 convert ----------------
__global__ __launch_bounds__(256) void cvt(const float* __restrict__ in,
                                           ushort* __restrict__ out, int n4) {
  const int i = blockIdx.x * 256 + threadIdx.x;
  if (i >= n4) return;
  const float4 v = ((const float4*)in)[i];
  ushort4 o;
  o.x = f2h(v.x); o.y = f2h(v.y); o.z = f2h(v.z); o.w = f2h(v.w);
  ((ushort4*)out)[i] = o;
}

// ---------------- GEMM 256x256, BK=32, 4-slot ring, 2x16-MFMA phases ------
// C[m][n] = sum_k A[m][k]*W[n][k]. 512 threads = 8 waves (2M x 4N), wave owns
// 128x64. LDS ring: 4 slots x (A 16KB + B 16KB) = 128KB. Group t computes
// buf[t%4], stages tile t+3. Phase A: {read bf[0..3]+af0[0..3] (8 b128) |
// stage A-tile (2 loads) | barrier | 16 MFMA}. Phase B: {read af1[0..3] (4,
// interleaves under A's MFMA cluster) | stage B-tile | vmcnt(8) counted |
// barrier | 16 MFMA}. 2 barriers/tile; vmcnt never drains (8/4/0 tail).
template <typename OutT>
__global__ __launch_bounds__(512, 2) void gemm256(const ushort* __restrict__ A,
                                                  const ushort* __restrict__ Bw,
                                                  OutT* __restrict__ C) {
  __shared__ ushort As[4][256 * 32];
  __shared__ ushort Bs[4][256 * 32];
  const int tid = threadIdx.x;                 // 0..511
  const int lane = tid & 63, wid = tid >> 6;   // 8 waves
  const int g = lane >> 4, q16 = lane & 15;
  const int wm = wid >> 2, wn = wid & 3;       // 2M x 4N

  const int flat = (int)blockIdx.x;            // 0..255
  const int xcd = flat & 7, idx = flat >> 3;   // idx 0..31
  const int bm = xcd * 4 + (idx & 3);          // 4 bm-panels per XCD
  const int bn = idx >> 2;                     // 0..7
  const ushort* Ab = A + (size_t)bm * 256 * Dc;
  const ushort* Bb = Bw + (size_t)bn * 256 * Dc;

#define STAGE1(KT, BUF, PH) do {                                               \
    const int pass_ = (PH) & 1;                                                \
    const int c_ = pass_ * 512 + tid;                                          \
    const int row_ = c_ >> 2, gl_ = c_ & 3;                                    \
    const int col_ = (KT) * 32 + ((gl_ ^ ((row_ >> 1) & 3)) << 3);             \
    if ((PH) < 2)                                                              \
      async_cp16(&As[BUF][(pass_ * 512 + wid * 64) * 8],                       \
                 Ab + (size_t)row_ * Dc + col_);                               \
    else                                                                       \
      async_cp16(&Bs[BUF][(pass_ * 512 + wid * 64) * 8],                       \
                 Bb + (size_t)row_ * Dc + col_);                               \
  } while (0)

  f32x4 acc[8][4] = {};

  // prologue: tiles 0,1,2 -> slots 0,1,2 (12 loads); wait tile0 only
  for (int tt = 0; tt < 3; ++tt) {
    STAGE1(tt, tt, 0); STAGE1(tt, tt, 1);
    STAGE1(tt, tt, 2); STAGE1(tt, tt, 3);
  }
  asm volatile("s_waitcnt vmcnt(8)" ::: "memory");   // tile0 landed; 1,2 fly
  __builtin_amdgcn_s_barrier();
  __builtin_amdgcn_sched_barrier(0);

  const int sgz = (g ^ ((q16 >> 1) & 3)) << 3;   // read granule (ushort off)

#pragma unroll 1
  for (int t = 0; t < 64; ++t) {
    const int rb = t & 3;
    const int sb = (t + 3) & 3;
    const bool st = (t + 3) < 64;
    const ushort* Asb = As[rb];
    const ushort* Bsb = Bs[rb];
    half8 af0[4], af1[4], bf[4];

    // ---- Phase A: B-cols + A-half0, stage A-tile, 16 MFMA ----
#pragma unroll
    for (int nf = 0; nf < 4; ++nf) {
      const int r = wn * 64 + nf * 16 + q16;
      bf[nf] = *(const half8*)&Bsb[r * 32 + sgz];
    }
#pragma unroll
    for (int mf = 0; mf < 4; ++mf) {
      const int r = wm * 128 + mf * 16 + q16;
      af0[mf] = *(const half8*)&Asb[r * 32 + sgz];
    }
    if (st) { STAGE1(t + 3, sb, 0); STAGE1(t + 3, sb, 1); }
    __builtin_amdgcn_s_barrier();
    __builtin_amdgcn_sched_barrier(0);
    __builtin_amdgcn_s_setprio(1);
#pragma unroll
    for (int mf = 0; mf < 4; ++mf)
#pragma unroll
      for (int nf = 0; nf < 4; ++nf)
        acc[mf][nf] = MFMA(af0[mf], bf[nf], acc[mf][nf]);
    __builtin_amdgcn_s_setprio(0);

    // ---- Phase B: A-half1 (overlaps A's MFMA), stage B-tile, 16 MFMA ----
#pragma unroll
    for (int mf = 0; mf < 4; ++mf) {
      const int r = wm * 128 + 64 + mf * 16 + q16;
      af1[mf] = *(const half8*)&Asb[r * 32 + sgz];
    }
    if (st) { STAGE1(t + 3, sb, 2); STAGE1(t + 3, sb, 3); }
    if (st)                asm volatile("s_waitcnt vmcnt(8)" ::: "memory");
    else if (t + 2 < 64)   asm volatile("s_waitcnt vmcnt(4)" ::: "memory");
    else if (t + 1 < 64)   asm volatile("s_waitcnt vmcnt(0)" ::: "memory");
    __builtin_amdgcn_s_barrier();
    __builtin_amdgcn_sched_barrier(0);
    __builtin_amdgcn_s_setprio(1);
#pragma unroll
    for (int mf = 0; mf < 4; ++mf)
#pragma unroll
      for (int nf = 0; nf < 4; ++nf)
        acc[4 + mf][nf] = MFMA(af1[mf], bf[nf], acc[4 + mf][nf]);
    __builtin_amdgcn_s_setprio(0);
  }
#undef STAGE1

  const int m00 = bm * 256 + wm * 128 + g * 4;
  const int n0 = bn * 256 + wn * 64 + q16;
#pragma unroll
  for (int mf = 0; mf < 8; ++mf)
#pragma unroll
    for (int nf = 0; nf < 4; ++nf) {
      const int m0 = m00 + mf * 16;
      const int n = n0 + nf * 16;
#pragma unroll
      for (int r = 0; r < 4; ++r) {
        const float v = acc[mf][nf][r];
        if constexpr (sizeof(OutT) == 2)
          C[(size_t)(m0 + r) * Dc + n] = (OutT)f2h(v);
        else
          C[(size_t)(m0 + r) * Dc + n] = (OutT)v;
      }
    }
}

// ---------------- RoPE in-place on [B,T,H,128] fp16 ----------------
__global__ __launch_bounds__(256) void rope(ushort* __restrict__ X,
                                            const float* __restrict__ cs,
                                            const float* __restrict__ sn) {
  const int tid = blockIdx.x * 256 + threadIdx.x;
  const int row = tid >> 4;
  const int jq = (tid & 15) << 2;
  const int t = (row >> 4) & (Tc - 1);
  ushort* base = X + (size_t)row * 128;
  const ushort4 lo = *(const ushort4*)(base + jq);
  const ushort4 hi = *(const ushort4*)(base + 64 + jq);
  const float4 c4 = *(const float4*)(cs + t * 128 + jq);
  const float4 s4 = *(const float4*)(sn + t * 128 + jq);
  const float xl[4] = {h2f(lo.x), h2f(lo.y), h2f(lo.z), h2f(lo.w)};
  const float xh[4] = {h2f(hi.x), h2f(hi.y), h2f(hi.z), h2f(hi.w)};
  const float cc[4] = {c4.x, c4.y, c4.z, c4.w};
  const float ss[4] = {s4.x, s4.y, s4.z, s4.w};
  ushort4 olo, ohi;
  ushort* po = (ushort*)&olo;
  ushort* ph = (ushort*)&ohi;
#pragma unroll
  for (int k = 0; k < 4; ++k) {
    po[k] = f2h(xl[k] * cc[k] - xh[k] * ss[k]);
    ph[k] = f2h(xh[k] * cc[k] + xl[k] * ss[k]);
  }
  *(ushort4*)(base + jq) = olo;
  *(ushort4*)(base + 64 + jq) = ohi;
}

// ---------------- causal flash attention (2 q-chains / wave) ----------------
// REVERTED to round-9 version (167us known-good). grid (4,64) = 256 blocks,
// 512 threads: 8 waves x 32 q-rows = 256-row supertile, paired {7-p, p}.
// Dual q-chains interleave softmax stalls and share K/V LDS reads. True reg
// footprint = VGPR 128 + ~64 acc (unified file) -> 2 waves/SIMD; occupancy
// lever is closed (round-10 ERRATA: forcing more waves => spill collapse).
__global__ __launch_bounds__(512, 2) void attn(const ushort* __restrict__ Q,
                                               const ushort* __restrict__ K,
                                               const ushort* __restrict__ V,
                                               ushort* __restrict__ O) {
  __shared__ ushort Ks[2][64 * 128];   // [kv][d], XOR-swizzled (granule ^= kv&7)
  __shared__ ushort Vt[2][128 * 64];   // [d][kv], XOR-swizzled rows

  const int tid = threadIdx.x;         // 0..511
  const int lane = tid & 63, wid = tid >> 6;   // wid 0..7
  const int g = lane >> 4, q16 = lane & 15;

  // head-major XCD swizzle over 256 blocks
  const int flat = (int)(blockIdx.x + 4 * blockIdx.y);    // 0..255
  const int xcd = flat & 7, idx = flat >> 3;              // idx 0..31
  const int bh = xcd + 8 * (idx & 7);                     // head-slot 0..63
  const int pr = idx >> 3;                                // supertile pair 0..3

  const int b = bh >> 4, h = bh & 15;
  const size_t headbase = ((size_t)b * Tc * Hc + h) * 128;  // t-stride = 2048
  const float SCL2 = 0.12751743f;      // log2(e)/sqrt(128)

  const int vdc = (wid & 3) * 4 + (lane & 3);         // 0..15: d = vdc*8..+7
  const int vkvp = (wid >> 2) * 16 + (lane >> 2);     // 0..31: kv pair

  uint4 vreg[2];

#define ISSUEK(KT, BUF) do {                                                   \
    const ushort* Kb_ = K + headbase + (size_t)(KT) * 64 * Dc;                 \
    _Pragma("unroll") for (int i_ = 0; i_ < 2; ++i_) {                         \
      const int c_ = i_ * 512 + tid;                                           \
      const int kv_ = c_ >> 4, gl_ = c_ & 15;                                  \
      async_cp16(&Ks[BUF][(i_ * 512 + wid * 64) * 8],                          \
                 Kb_ + (size_t)kv_ * Dc + ((gl_ ^ (kv_ & 7)) << 3));           \
    }                                                                          \
  } while (0)

#define LOADV(KT) do {                                                         \
    const ushort* p0_ = V + headbase + (size_t)((KT) * 64 + 2 * vkvp) * Dc +   \
                        vdc * 8;                                               \
    vreg[0] = *(const uint4*)p0_;                                              \
    vreg[1] = *(const uint4*)(p0_ + Dc);                                       \
  } while (0)

#define WRITEV(BUF) do {                                                       \
    const ushort* e0_ = (const ushort*)&vreg[0];                               \
    const ushort* e1_ = (const ushort*)&vreg[1];                               \
    _Pragma("unroll") for (int j_ = 0; j_ < 8; ++j_) {                         \
      const int d_ = vdc * 8 + j_;                                             \
      const unsigned w_ = (unsigned)e0_[j_] | ((unsigned)e1_[j_] << 16);       \
      *(unsigned*)&Vt[BUF][(d_ * 64 + 2 * vkvp) ^ ((d_ & 7) << 3)] = w_;       \
    }                                                                          \
  } while (0)

#pragma unroll 1
  for (int half = 0; half < 2; ++half) {
    const int q0 = (half ? pr : 7 - pr) * 256;
    const int qrow = q0 + wid * 32;          // wave owns rows qrow..qrow+31
    const int nt = q0 / 64 + 4;

    // Q fragments, 2 chains (B-op: col=q=lane&15, k=d=g*8+j)
    half8 qreg[2][4];
#pragma unroll
    for (int qf = 0; qf < 2; ++qf)
#pragma unroll
      for (int ds = 0; ds < 4; ++ds)
        qreg[qf][ds] = *(const half8*)(Q + headbase +
                       (size_t)(qrow + qf * 16 + q16) * Dc + ds * 32 + g * 8);

    f32x4 oacc[2][8] = {};             // O^T frags: row=d (g*4+r), col=q
    float m_[2] = {-1e30f, -1e30f};
    float l_[2] = {0.f, 0.f};          // per-lane partials

    __builtin_amdgcn_s_barrier();      // prior half done reading all LDS bufs
    __builtin_amdgcn_sched_barrier(0);
    ISSUEK(0, 0);
    LOADV(0);
    WRITEV(0);                         // compiler waits vmcnt for vreg here

#pragma unroll 1
    for (int kt = 0; kt < nt; ++kt) {
      const int cur = kt & 1;
      const int kv0 = kt * 64;
      asm volatile("s_waitcnt vmcnt(0) lgkmcnt(0)" ::: "memory");
      __builtin_amdgcn_s_barrier();
      __builtin_amdgcn_sched_barrier(0);
      if (kt + 1 < nt) {
        ISSUEK(kt + 1, cur ^ 1);
        LOADV(kt + 1);
      }

      if (kv0 <= qrow + 31) {          // wave-uniform
        const ushort* Ksb = Ks[cur];
        const ushort* Vtb = Vt[cur];
        // S^T = K Q^T, both chains share kf
        f32x4 s[2][4] = {};
        __builtin_amdgcn_s_setprio(1);
#pragma unroll
        for (int ds = 0; ds < 4; ++ds) {
          half8 kf[4];
#pragma unroll
          for (int kvf = 0; kvf < 4; ++kvf) {
            const int kv = kvf * 16 + q16;
            kf[kvf] = *(const half8*)&Ksb[(kv * 128 + ds * 32 + g * 8) ^ ((kv & 7) << 3)];
          }
#pragma unroll
          for (int kvf = 0; kvf < 4; ++kvf)
#pragma unroll
            for (int qf = 0; qf < 2; ++qf)
              s[qf][kvf] = MFMA(kf[kvf], qreg[qf][ds], s[qf][kvf]);
        }
        __builtin_amdgcn_s_setprio(0);
        // causal mask + running max; mask only on diagonal tiles
        float pmax[2] = {-1e30f, -1e30f};
        if (kv0 + 63 > qrow) {
#pragma unroll
          for (int qf = 0; qf < 2; ++qf) {
            const int qg = qrow + qf * 16 + q16;
#pragma unroll
            for (int kvf = 0; kvf < 4; ++kvf)
#pragma unroll
              for (int r = 0; r < 4; ++r) {
                float v = s[qf][kvf][r];
                if ((kv0 + kvf * 16 + g * 4 + r) > qg) v = -1e30f;
                s[qf][kvf][r] = v;
                pmax[qf] = fmaxf(pmax[qf], v);
              }
          }
        } else {
#pragma unroll
          for (int qf = 0; qf < 2; ++qf)
#pragma unroll
            for (int kvf = 0; kvf < 4; ++kvf)
#pragma unroll
              for (int r = 0; r < 4; ++r)
                pmax[qf] = fmaxf(pmax[qf], s[qf][kvf][r]);
        }
#pragma unroll
        for (int qf = 0; qf < 2; ++qf) {
          pmax[qf] = fmaxf(pmax[qf], __shfl_xor(pmax[qf], 16));
          pmax[qf] = fmaxf(pmax[qf], __shfl_xor(pmax[qf], 32));
        }
        // T13 defer-max (joint trigger)
        if (!__all((pmax[0] <= m_[0] + 16.f) & (pmax[1] <= m_[1] + 16.f))) {
#pragma unroll
          for (int qf = 0; qf < 2; ++qf) {
            const float mn2 = fmaxf(m_[qf], pmax[qf]);
            const float alpha = __builtin_exp2f((m_[qf] - mn2) * SCL2);
            m_[qf] = mn2;
            l_[qf] *= alpha;
#pragma unroll
            for (int df = 0; df < 8; ++df)
              oacc[qf][df] *= alpha;
          }
        }
        // exp + pack, both chains
        uint w[2][4][2];
#pragma unroll
        for (int qf = 0; qf < 2; ++qf) {
          const float mn = m_[qf];
          float lsum = 0.f;
#pragma unroll
          for (int kvf = 0; kvf < 4; ++kvf) {
            const float p0 = __builtin_exp2f((s[qf][kvf][0] - mn) * SCL2);
            const float p1 = __builtin_exp2f((s[qf][kvf][1] - mn) * SCL2);
            const float p2 = __builtin_exp2f((s[qf][kvf][2] - mn) * SCL2);
            const float p3 = __builtin_exp2f((s[qf][kvf][3] - mn) * SCL2);
            lsum += (p0 + p1) + (p2 + p3);
            w[qf][kvf][0] = (unsigned)f2h(p0) | ((unsigned)f2h(p1) << 16);
            w[qf][kvf][1] = (unsigned)f2h(p2) | ((unsigned)f2h(p3) << 16);
          }
          l_[qf] += lsum;
        }
        // In-register P redistribution -> PV B-frags (per chain).
        const bool ghi = g >= 2;
        const bool godd = (g & 1) != 0;
        half8 pb[2][2];
#pragma unroll
        for (int qf = 0; qf < 2; ++qf) {
          uint sA[2][2], sB[2][2];
#pragma unroll
          for (int c = 0; c < 2; ++c)
#pragma unroll
            for (int i = 0; i < 2; ++i) {
              sA[c][i] = ghi ? w[qf][2 * c + 1][i] : w[qf][2 * c][i];
              sB[c][i] = ghi ? w[qf][2 * c][i] : w[qf][2 * c + 1][i];
            }
          uint x16[2][2], x32[2][2], x48[2][2];
#pragma unroll
          for (int c = 0; c < 2; ++c)
#pragma unroll
            for (int i = 0; i < 2; ++i) {
              x16[c][i] = __shfl_xor(sA[c][i], 16);
              x32[c][i] = __shfl_xor(sB[c][i], 32);
              x48[c][i] = __shfl_xor(sB[c][i], 48);
            }
#pragma unroll
          for (int c = 0; c < 2; ++c) {
            uint4 t;
            t.x = godd ? (ghi ? x16[c][0] : x48[c][0]) : (ghi ? x32[c][0] : sA[c][0]);
            t.y = godd ? (ghi ? x16[c][1] : x48[c][1]) : (ghi ? x32[c][1] : sA[c][1]);
            t.z = godd ? (ghi ? sA[c][0] : x32[c][0]) : (ghi ? x48[c][0] : x16[c][0]);
            t.w = godd ? (ghi ? sA[c][1] : x32[c][1]) : (ghi ? x48[c][1] : x16[c][1]);
            pb[qf][c] = __builtin_bit_cast(half8, t);
          }
        }
        // O^T += V^T P^T, both chains share vf
        __builtin_amdgcn_s_setprio(1);
#pragma unroll
        for (int c = 0; c < 2; ++c) {
#pragma unroll
          for (int df = 0; df < 8; ++df) {
            const int d = df * 16 + q16;
            const half8 vf = *(const half8*)&Vtb[(d * 64 + c * 32 + g * 8) ^ ((d & 7) << 3)];
#pragma unroll
            for (int qf = 0; qf < 2; ++qf)
              oacc[qf][df] = MFMA(vf, pb[qf][c], oacc[qf][df]);
          }
        }
        __builtin_amdgcn_s_setprio(0);
      }

      if (kt + 1 < nt) WRITEV(cur ^ 1);   // vreg vmcnt wait lands here, hidden
    }

    // epilogue: reduce per-lane l partials, store O fp16
#pragma unroll
    for (int qf = 0; qf < 2; ++qf) {
      float l = l_[qf];
      l += __shfl_xor(l, 16);
      l += __shfl_xor(l, 32);
      const float inv = 1.0f / l;
      const int t = qrow + qf * 16 + q16;
#pragma unroll
      for (int df = 0; df < 8; ++df) {
        const f32x4 v = oacc[qf][df];
        ushort4 o;
        o.x = f2h(v[0] * inv); o.y = f2h(v[1] * inv);
        o.z = f2h(v[2] * inv); o.w = f2h(v[3] * inv);
        *(ushort4*)(O + headbase + (size_t)t * Dc + df * 16 + g * 4) = o;
      }
    }
  }
#undef ISSUEK
#undef LOADV
#undef WRITEV
}

extern "C" void kernel_launch(void* const* d_in, const int* in_sizes, int n_in,
                              void* d_out, int out_size, void* d_ws, size_t ws_size,
                              hipStream_t stream) {
  (void)in_sizes; (void)n_in; (void)out_size; (void)ws_size;
  const float* x  = (const float*)d_in[0];
  const float* cs = (const float*)d_in[1];
  const float* sn = (const float*)d_in[2];
  // d_in[3] = mask (unused: causal handled analytically)
  const float* Wq = (const float*)d_in[4];
  const float* Wk = (const float*)d_in[5];
  const float* Wv = (const float*)d_in[6];
  const float* Wo = (const float*)d_in[7];
  float* out = (float*)d_out;

  char* ws = (char*)d_ws;
  const size_t MB = 1024 * 1024;
  ushort* xb  = (ushort*)(ws);            // 32MB x fp16; reused as attn output O
  ushort* wqb = (ushort*)(ws + 32 * MB);
  ushort* wkb = (ushort*)(ws + 40 * MB);
  ushort* wvb = (ushort*)(ws + 48 * MB);
  ushort* wob = (ushort*)(ws + 56 * MB);
  ushort* Qr  = (ushort*)(ws + 64 * MB);  // 32MB each, [B,T,H,128] fp16
  ushort* Kr  = (ushort*)(ws + 96 * MB);
  ushort* Vr  = (ushort*)(ws + 128 * MB); // end: 160MB

  cvt<<<16384, 256, 0, stream>>>(x, xb, 4194304);
  cvt<<<4096, 256, 0, stream>>>(Wq, wqb, 1048576);
  cvt<<<4096, 256, 0, stream>>>(Wk, wkb, 1048576);
  cvt<<<4096, 256, 0, stream>>>(Wv, wvb, 1048576);
  cvt<<<4096, 256, 0, stream>>>(Wo, wob, 1048576);

  gemm256<ushort><<<256, 512, 0, stream>>>(xb, wqb, Qr);
  gemm256<ushort><<<256, 512, 0, stream>>>(xb, wkb, Kr);
  gemm256<ushort><<<256, 512, 0, stream>>>(xb, wvb, Vr);

  rope<<<8192, 256, 0, stream>>>(Qr, cs, sn);
  rope<<<8192, 256, 0, stream>>>(Kr, cs, sn);

  attn<<<dim3(4, 64), 512, 0, stream>>>(Qr, Kr, Vr, xb);

  gemm256<float><<<256, 512, 0, stream>>>(xb, wob, out);
}

// Round 12
// 471.633 us; speedup vs baseline: 1.7407x; 1.0139x over previous
//
#include <hip/hip_runtime.h>
#include <hip/hip_bf16.h>

#define DEV static __device__ __forceinline__

typedef __attribute__((ext_vector_type(8))) _Float16 half8;   // A/B frag: 8 fp16 = 4 VGPR
typedef __attribute__((ext_vector_type(4))) float f32x4;      // C/D frag

constexpr int Bc = 4, Tc = 2048, Dc = 2048, Hc = 16;          // HD = 128

DEV ushort f2h(float f) { _Float16 h = (_Float16)f; return __builtin_bit_cast(ushort, h); }
DEV float  h2f(ushort u) { return (float)__builtin_bit_cast(_Float16, u); }
DEV uint pk2h(float a, float b) {
  return __builtin_bit_cast(uint, __builtin_amdgcn_cvt_pkrtz(a, b));
}

DEV f32x4 MFMA(half8 a, half8 b, f32x4 c) {
  return __builtin_amdgcn_mfma_f32_16x16x32_f16(a, b, c, 0, 0, 0);
}

DEV void async_cp16(void* lds, const void* g) {
  __builtin_amdgcn_global_load_lds((const __attribute__((address_space(1))) void*)g,
                                   (__attribute__((address_space(3))) void*)lds,
                                   16, 0, 0);
}

// ---------------- f32 -> fp16 convert ----------------
__global__ __launch_bounds__(256) void cvt(const float* __restrict__ in,
                                           ushort* __restrict__ out, int n4) {
  const int i = blockIdx.x * 256 + threadIdx.x;
  if (i >= n4) return;
  const float4 v = ((const float4*)in)[i];
  ushort4 o;
  o.x = f2h(v.x); o.y = f2h(v.y); o.z = f2h(v.z); o.w = f2h(v.w);
  ((ushort4*)out)[i] = o;
}

// ---------------- GEMM 256x256, BK=32, 4-slot ring, 1 barrier/tile --------
// C[m][n] = sum_k A[m][k]*W[n][k]. 512 threads = 8 waves (2M x 4N), wave owns
// 128x64. LDS ring: 4 slots x 32KB = 128KB. Iter t: vmcnt(8) [tile t landed;
// t+1,t+2 in flight] | barrier [all waves past tile t-1 reads -> slot
// (t+3)&3=(t-1)&3 free] | issue all 12 ds_reads | stage tile t+3 (4 loads) |
// 32 MFMA (compiler emits fine-grained lgkmcnt: first cluster waits 8 reads,
// second 0). ONE barrier per K-tile (round-11 evidence: fewer barriers won).
template <typename OutT>
__global__ __launch_bounds__(512, 2) void gemm256(const ushort* __restrict__ A,
                                                  const ushort* __restrict__ Bw,
                                                  OutT* __restrict__ C) {
  __shared__ ushort As[4][256 * 32];
  __shared__ ushort Bs[4][256 * 32];
  const int tid = threadIdx.x;                 // 0..511
  const int lane = tid & 63, wid = tid >> 6;   // 8 waves
  const int g = lane >> 4, q16 = lane & 15;
  const int wm = wid >> 2, wn = wid & 3;       // 2M x 4N

  const int flat = (int)blockIdx.x;            // 0..255
  const int xcd = flat & 7, idx = flat >> 3;   // idx 0..31
  const int bm = xcd * 4 + (idx & 3);          // 4 bm-panels per XCD
  const int bn = idx >> 2;                     // 0..7
  const ushort* Ab = A + (size_t)bm * 256 * Dc;
  const ushort* Bb = Bw + (size_t)bn * 256 * Dc;

#define STAGE1(KT, BUF, PH) do {                                               \
    const int pass_ = (PH) & 1;                                                \
    const int c_ = pass_ * 512 + tid;                                          \
    const int row_ = c_ >> 2, gl_ = c_ & 3;                                    \
    const int col_ = (KT) * 32 + ((gl_ ^ ((row_ >> 1) & 3)) << 3);             \
    if ((PH) < 2)                                                              \
      async_cp16(&As[BUF][(pass_ * 512 + wid * 64) * 8],                       \
                 Ab + (size_t)row_ * Dc + col_);                               \
    else                                                                       \
      async_cp16(&Bs[BUF][(pass_ * 512 + wid * 64) * 8],                       \
                 Bb + (size_t)row_ * Dc + col_);                               \
  } while (0)

  f32x4 acc[8][4] = {};

  // prologue: tiles 0,1,2 -> slots 0,1,2 (12 loads per wave-lane group)
  for (int tt = 0; tt < 3; ++tt) {
    STAGE1(tt, tt, 0); STAGE1(tt, tt, 1);
    STAGE1(tt, tt, 2); STAGE1(tt, tt, 3);
  }

  const int sgz = (g ^ ((q16 >> 1) & 3)) << 3;   // read granule (ushort off)

#pragma unroll 1
  for (int t = 0; t < 64; ++t) {
    const int rb = t & 3;
    const int sb = (t + 3) & 3;
    const bool st = (t + 3) < 64;
    const ushort* Asb = As[rb];
    const ushort* Bsb = Bs[rb];

    // tile t landed; keep 2 tiles in flight (8 loads). Tail: 4 then 0.
    if (t + 2 < 64)      asm volatile("s_waitcnt vmcnt(8)" ::: "memory");
    else if (t + 1 < 64) asm volatile("s_waitcnt vmcnt(4)" ::: "memory");
    else                 asm volatile("s_waitcnt vmcnt(0)" ::: "memory");
    __builtin_amdgcn_s_barrier();
    __builtin_amdgcn_sched_barrier(0);

    half8 af0[4], af1[4], bf[4];
#pragma unroll
    for (int nf = 0; nf < 4; ++nf) {
      const int r = wn * 64 + nf * 16 + q16;
      bf[nf] = *(const half8*)&Bsb[r * 32 + sgz];
    }
#pragma unroll
    for (int mf = 0; mf < 4; ++mf) {
      const int r = wm * 128 + mf * 16 + q16;
      af0[mf] = *(const half8*)&Asb[r * 32 + sgz];
    }
#pragma unroll
    for (int mf = 0; mf < 4; ++mf) {
      const int r = wm * 128 + 64 + mf * 16 + q16;
      af1[mf] = *(const half8*)&Asb[r * 32 + sgz];
    }
    if (st) { STAGE1(t + 3, sb, 0); STAGE1(t + 3, sb, 1);
              STAGE1(t + 3, sb, 2); STAGE1(t + 3, sb, 3); }

    __builtin_amdgcn_s_setprio(1);
#pragma unroll
    for (int mf = 0; mf < 4; ++mf)
#pragma unroll
      for (int nf = 0; nf < 4; ++nf)
        acc[mf][nf] = MFMA(af0[mf], bf[nf], acc[mf][nf]);
#pragma unroll
    for (int mf = 0; mf < 4; ++mf)
#pragma unroll
      for (int nf = 0; nf < 4; ++nf)
        acc[4 + mf][nf] = MFMA(af1[mf], bf[nf], acc[4 + mf][nf]);
    __builtin_amdgcn_s_setprio(0);
  }
#undef STAGE1

  const int m00 = bm * 256 + wm * 128 + g * 4;
  const int n0 = bn * 256 + wn * 64 + q16;
#pragma unroll
  for (int mf = 0; mf < 8; ++mf)
#pragma unroll
    for (int nf = 0; nf < 4; ++nf) {
      const int m0 = m00 + mf * 16;
      const int n = n0 + nf * 16;
#pragma unroll
      for (int r = 0; r < 4; ++r) {
        const float v = acc[mf][nf][r];
        if constexpr (sizeof(OutT) == 2)
          C[(size_t)(m0 + r) * Dc + n] = (OutT)f2h(v);
        else
          C[(size_t)(m0 + r) * Dc + n] = (OutT)v;
      }
    }
}

// ---------------- RoPE in-place on [B,T,H,128] fp16 ----------------
__global__ __launch_bounds__(256) void rope(ushort* __restrict__ X,
                                            const float* __restrict__ cs,
                                            const float* __restrict__ sn) {
  const int tid = blockIdx.x * 256 + threadIdx.x;
  const int row = tid >> 4;
  const int jq = (tid & 15) << 2;
  const int t = (row >> 4) & (Tc - 1);
  ushort* base = X + (size_t)row * 128;
  const ushort4 lo = *(const ushort4*)(base + jq);
  const ushort4 hi = *(const ushort4*)(base + 64 + jq);
  const float4 c4 = *(const float4*)(cs + t * 128 + jq);
  const float4 s4 = *(const float4*)(sn + t * 128 + jq);
  const float xl[4] = {h2f(lo.x), h2f(lo.y), h2f(lo.z), h2f(lo.w)};
  const float xh[4] = {h2f(hi.x), h2f(hi.y), h2f(hi.z), h2f(hi.w)};
  const float cc[4] = {c4.x, c4.y, c4.z, c4.w};
  const float ss[4] = {s4.x, s4.y, s4.z, s4.w};
  ushort4 olo, ohi;
  ushort* po = (ushort*)&olo;
  ushort* ph = (ushort*)&ohi;
#pragma unroll
  for (int k = 0; k < 4; ++k) {
    po[k] = f2h(xl[k] * cc[k] - xh[k] * ss[k]);
    ph[k] = f2h(xh[k] * cc[k] + xl[k] * ss[k]);
  }
  *(ushort4*)(base + jq) = olo;
  *(ushort4*)(base + 64 + jq) = ohi;
}

// ---------------- causal flash attention (2 q-chains / wave) ----------------
// Round-9 structure (known-good 167us) + pkrtz packing (VALU reduction only).
// grid (4,64) = 256 blocks, 512 threads: 8 waves x 32 q-rows = 256-row
// supertile, paired {7-p, p}. Dual q-chains interleave softmax stalls and
// share K/V LDS reads. Reg footprint (VGPR 128 + ~64 acc) -> 2 waves/SIMD;
// occupancy lever closed (round-10: forcing more waves => spill collapse).
__global__ __launch_bounds__(512, 2) void attn(const ushort* __restrict__ Q,
                                               const ushort* __restrict__ K,
                                               const ushort* __restrict__ V,
                                               ushort* __restrict__ O) {
  __shared__ ushort Ks[2][64 * 128];   // [kv][d], XOR-swizzled (granule ^= kv&7)
  __shared__ ushort Vt[2][128 * 64];   // [d][kv], XOR-swizzled rows

  const int tid = threadIdx.x;         // 0..511
  const int lane = tid & 63, wid = tid >> 6;   // wid 0..7
  const int g = lane >> 4, q16 = lane & 15;

  // head-major XCD swizzle over 256 blocks
  const int flat = (int)(blockIdx.x + 4 * blockIdx.y);    // 0..255
  const int xcd = flat & 7, idx = flat >> 3;              // idx 0..31
  const int bh = xcd + 8 * (idx & 7);                     // head-slot 0..63
  const int pr = idx >> 3;                                // supertile pair 0..3

  const int b = bh >> 4, h = bh & 15;
  const size_t headbase = ((size_t)b * Tc * Hc + h) * 128;  // t-stride = 2048
  const float SCL2 = 0.12751743f;      // log2(e)/sqrt(128)

  const int vdc = (wid & 3) * 4 + (lane & 3);         // 0..15: d = vdc*8..+7
  const int vkvp = (wid >> 2) * 16 + (lane >> 2);     // 0..31: kv pair

  uint4 vreg[2];

#define ISSUEK(KT, BUF) do {                                                   \
    const ushort* Kb_ = K + headbase + (size_t)(KT) * 64 * Dc;                 \
    _Pragma("unroll") for (int i_ = 0; i_ < 2; ++i_) {                         \
      const int c_ = i_ * 512 + tid;                                           \
      const int kv_ = c_ >> 4, gl_ = c_ & 15;                                  \
      async_cp16(&Ks[BUF][(i_ * 512 + wid * 64) * 8],                          \
                 Kb_ + (size_t)kv_ * Dc + ((gl_ ^ (kv_ & 7)) << 3));           \
    }                                                                          \
  } while (0)

#define LOADV(KT) do {                                                         \
    const ushort* p0_ = V + headbase + (size_t)((KT) * 64 + 2 * vkvp) * Dc +   \
                        vdc * 8;                                               \
    vreg[0] = *(const uint4*)p0_;                                              \
    vreg[1] = *(const uint4*)(p0_ + Dc);                                       \
  } while (0)

#define WRITEV(BUF) do {                                                       \
    const ushort* e0_ = (const ushort*)&vreg[0];                               \
    const ushort* e1_ = (const ushort*)&vreg[1];                               \
    _Pragma("unroll") for (int j_ = 0; j_ < 8; ++j_) {                         \
      const int d_ = vdc * 8 + j_;                                             \
      const unsigned w_ = (unsigned)e0_[j_] | ((unsigned)e1_[j_] << 16);       \
      *(unsigned*)&Vt[BUF][(d_ * 64 + 2 * vkvp) ^ ((d_ & 7) << 3)] = w_;       \
    }                                                                          \
  } while (0)

#pragma unroll 1
  for (int half = 0; half < 2; ++half) {
    const int q0 = (half ? pr : 7 - pr) * 256;
    const int qrow = q0 + wid * 32;          // wave owns rows qrow..qrow+31
    const int nt = q0 / 64 + 4;

    // Q fragments, 2 chains (B-op: col=q=lane&15, k=d=g*8+j)
    half8 qreg[2][4];
#pragma unroll
    for (int qf = 0; qf < 2; ++qf)
#pragma unroll
      for (int ds = 0; ds < 4; ++ds)
        qreg[qf][ds] = *(const half8*)(Q + headbase +
                       (size_t)(qrow + qf * 16 + q16) * Dc + ds * 32 + g * 8);

    f32x4 oacc[2][8] = {};             // O^T frags: row=d (g*4+r), col=q
    float m_[2] = {-1e30f, -1e30f};
    float l_[2] = {0.f, 0.f};          // per-lane partials

    __builtin_amdgcn_s_barrier();      // prior half done reading all LDS bufs
    __builtin_amdgcn_sched_barrier(0);
    ISSUEK(0, 0);
    LOADV(0);
    WRITEV(0);                         // compiler waits vmcnt for vreg here

#pragma unroll 1
    for (int kt = 0; kt < nt; ++kt) {
      const int cur = kt & 1;
      const int kv0 = kt * 64;
      asm volatile("s_waitcnt vmcnt(0) lgkmcnt(0)" ::: "memory");
      __builtin_amdgcn_s_barrier();
      __builtin_amdgcn_sched_barrier(0);
      if (kt + 1 < nt) {
        ISSUEK(kt + 1, cur ^ 1);
        LOADV(kt + 1);
      }

      if (kv0 <= qrow + 31) {          // wave-uniform
        const ushort* Ksb = Ks[cur];
        const ushort* Vtb = Vt[cur];
        // S^T = K Q^T, both chains share kf
        f32x4 s[2][4] = {};
        __builtin_amdgcn_s_setprio(1);
#pragma unroll
        for (int ds = 0; ds < 4; ++ds) {
          half8 kf[4];
#pragma unroll
          for (int kvf = 0; kvf < 4; ++kvf) {
            const int kv = kvf * 16 + q16;
            kf[kvf] = *(const half8*)&Ksb[(kv * 128 + ds * 32 + g * 8) ^ ((kv & 7) << 3)];
          }
#pragma unroll
          for (int kvf = 0; kvf < 4; ++kvf)
#pragma unroll
            for (int qf = 0; qf < 2; ++qf)
              s[qf][kvf] = MFMA(kf[kvf], qreg[qf][ds], s[qf][kvf]);
        }
        __builtin_amdgcn_s_setprio(0);
        // causal mask + running max; mask only on diagonal tiles
        float pmax[2] = {-1e30f, -1e30f};
        if (kv0 + 63 > qrow) {
#pragma unroll
          for (int qf = 0; qf < 2; ++qf) {
            const int qg = qrow + qf * 16 + q16;
#pragma unroll
            for (int kvf = 0; kvf < 4; ++kvf)
#pragma unroll
              for (int r = 0; r < 4; ++r) {
                float v = s[qf][kvf][r];
                if ((kv0 + kvf * 16 + g * 4 + r) > qg) v = -1e30f;
                s[qf][kvf][r] = v;
                pmax[qf] = fmaxf(pmax[qf], v);
              }
          }
        } else {
#pragma unroll
          for (int qf = 0; qf < 2; ++qf)
#pragma unroll
            for (int kvf = 0; kvf < 4; ++kvf)
#pragma unroll
              for (int r = 0; r < 4; ++r)
                pmax[qf] = fmaxf(pmax[qf], s[qf][kvf][r]);
        }
#pragma unroll
        for (int qf = 0; qf < 2; ++qf) {
          pmax[qf] = fmaxf(pmax[qf], __shfl_xor(pmax[qf], 16));
          pmax[qf] = fmaxf(pmax[qf], __shfl_xor(pmax[qf], 32));
        }
        // T13 defer-max (joint trigger)
        if (!__all((pmax[0] <= m_[0] + 16.f) & (pmax[1] <= m_[1] + 16.f))) {
#pragma unroll
          for (int qf = 0; qf < 2; ++qf) {
            const float mn2 = fmaxf(m_[qf], pmax[qf]);
            const float alpha = __builtin_exp2f((m_[qf] - mn2) * SCL2);
            m_[qf] = mn2;
            l_[qf] *= alpha;
#pragma unroll
            for (int df = 0; df < 8; ++df)
              oacc[qf][df] *= alpha;
          }
        }
        // exp + pkrtz pack, both chains
        uint w[2][4][2];
#pragma unroll
        for (int qf = 0; qf < 2; ++qf) {
          const float mn = m_[qf];
          float lsum = 0.f;
#pragma unroll
          for (int kvf = 0; kvf < 4; ++kvf) {
            const float p0 = __builtin_exp2f((s[qf][kvf][0] - mn) * SCL2);
            const float p1 = __builtin_exp2f((s[qf][kvf][1] - mn) * SCL2);
            const float p2 = __builtin_exp2f((s[qf][kvf][2] - mn) * SCL2);
            const float p3 = __builtin_exp2f((s[qf][kvf][3] - mn) * SCL2);
            lsum += (p0 + p1) + (p2 + p3);
            w[qf][kvf][0] = pk2h(p0, p1);
            w[qf][kvf][1] = pk2h(p2, p3);
          }
          l_[qf] += lsum;
        }
        // In-register P redistribution -> PV B-frags (per chain).
        const bool ghi = g >= 2;
        const bool godd = (g & 1) != 0;
        half8 pb[2][2];
#pragma unroll
        for (int qf = 0; qf < 2; ++qf) {
          uint sA[2][2], sB[2][2];
#pragma unroll
          for (int c = 0; c < 2; ++c)
#pragma unroll
            for (int i = 0; i < 2; ++i) {
              sA[c][i] = ghi ? w[qf][2 * c + 1][i] : w[qf][2 * c][i];
              sB[c][i] = ghi ? w[qf][2 * c][i] : w[qf][2 * c + 1][i];
            }
          uint x16[2][2], x32[2][2], x48[2][2];
#pragma unroll
          for (int c = 0; c < 2; ++c)
#pragma unroll
            for (int i = 0; i < 2; ++i) {
              x16[c][i] = __shfl_xor(sA[c][i], 16);
              x32[c][i] = __shfl_xor(sB[c][i], 32);
              x48[c][i] = __shfl_xor(sB[c][i], 48);
            }
#pragma unroll
          for (int c = 0; c < 2; ++c) {
            uint4 t;
            t.x = godd ? (ghi ? x16[c][0] : x48[c][0]) : (ghi ? x32[c][0] : sA[c][0]);
            t.y = godd ? (ghi ? x16[c][1] : x48[c][1]) : (ghi ? x32[c][1] : sA[c][1]);
            t.z = godd ? (ghi ? sA[c][0] : x32[c][0]) : (ghi ? x48[c][0] : x16[c][0]);
            t.w = godd ? (ghi ? sA[c][1] : x32[c][1]) : (ghi ? x48[c][1] : x16[c][1]);
            pb[qf][c] = __builtin_bit_cast(half8, t);
          }
        }
        // O^T += V^T P^T, both chains share vf
        __builtin_amdgcn_s_setprio(1);
#pragma unroll
        for (int c = 0; c < 2; ++c) {
#pragma unroll
          for (int df = 0; df < 8; ++df) {
            const int d = df * 16 + q16;
            const half8 vf = *(const half8*)&Vtb[(d * 64 + c * 32 + g * 8) ^ ((d & 7) << 3)];
#pragma unroll
            for (int qf = 0; qf < 2; ++qf)
              oacc[qf][df] = MFMA(vf, pb[qf][c], oacc[qf][df]);
          }
        }
        __builtin_amdgcn_s_setprio(0);
      }

      if (kt + 1 < nt) WRITEV(cur ^ 1);   // vreg vmcnt wait lands here, hidden
    }

    // epilogue: reduce per-lane l partials, store O fp16
#pragma unroll
    for (int qf = 0; qf < 2; ++qf) {
      float l = l_[qf];
      l += __shfl_xor(l, 16);
      l += __shfl_xor(l, 32);
      const float inv = 1.0f / l;
      const int t = qrow + qf * 16 + q16;
#pragma unroll
      for (int df = 0; df < 8; ++df) {
        const f32x4 v = oacc[qf][df];
        ushort4 o;
        o.x = f2h(v[0] * inv); o.y = f2h(v[1] * inv);
        o.z = f2h(v[2] * inv); o.w = f2h(v[3] * inv);
        *(ushort4*)(O + headbase + (size_t)t * Dc + df * 16 + g * 4) = o;
      }
    }
  }
#undef ISSUEK
#undef LOADV
#undef WRITEV
}

extern "C" void kernel_launch(void* const* d_in, const int* in_sizes, int n_in,
                              void* d_out, int out_size, void* d_ws, size_t ws_size,
                              hipStream_t stream) {
  (void)in_sizes; (void)n_in; (void)out_size; (void)ws_size;
  const float* x  = (const float*)d_in[0];
  const float* cs = (const float*)d_in[1];
  const float* sn = (const float*)d_in[2];
  // d_in[3] = mask (unused: causal handled analytically)
  const float* Wq = (const float*)d_in[4];
  const float* Wk = (const float*)d_in[5];
  const float* Wv = (const float*)d_in[6];
  const float* Wo = (const float*)d_in[7];
  float* out = (float*)d_out;

  char* ws = (char*)d_ws;
  const size_t MB = 1024 * 1024;
  ushort* xb  = (ushort*)(ws);            // 32MB x fp16; reused as attn output O
  ushort* wqb = (ushort*)(ws + 32 * MB);
  ushort* wkb = (ushort*)(ws + 40 * MB);
  ushort* wvb = (ushort*)(ws + 48 * MB);
  ushort* wob = (ushort*)(ws + 56 * MB);
  ushort* Qr  = (ushort*)(ws + 64 * MB);  // 32MB each, [B,T,H,128] fp16
  ushort* Kr  = (ushort*)(ws + 96 * MB);
  ushort* Vr  = (ushort*)(ws + 128 * MB); // end: 160MB

  cvt<<<16384, 256, 0, stream>>>(x, xb, 4194304);
  cvt<<<4096, 256, 0, stream>>>(Wq, wqb, 1048576);
  cvt<<<4096, 256, 0, stream>>>(Wk, wkb, 1048576);
  cvt<<<4096, 256, 0, stream>>>(Wv, wvb, 1048576);
  cvt<<<4096, 256, 0, stream>>>(Wo, wob, 1048576);

  gemm256<ushort><<<256, 512, 0, stream>>>(xb, wqb, Qr);
  gemm256<ushort><<<256, 512, 0, stream>>>(xb, wkb, Kr);
  gemm256<ushort><<<256, 512, 0, stream>>>(xb, wvb, Vr);

  rope<<<8192, 256, 0, stream>>>(Qr, cs, sn);
  rope<<<8192, 256, 0, stream>>>(Kr, cs, sn);

  attn<<<dim3(4, 64), 512, 0, stream>>>(Qr, Kr, Vr, xb);

  gemm256<float><<<256, 512, 0, stream>>>(xb, wob, out);
}

// Round 13
// 456.359 us; speedup vs baseline: 1.7989x; 1.0335x over previous
//
#include <hip/hip_runtime.h>
#include <hip/hip_bf16.h>

#define DEV static __device__ __forceinline__

typedef __attribute__((ext_vector_type(8))) _Float16 half8;   // A/B frag: 8 fp16 = 4 VGPR
typedef __attribute__((ext_vector_type(4))) float f32x4;      // C/D frag

constexpr int Bc = 4, Tc = 2048, Dc = 2048, Hc = 16;          // HD = 128

DEV ushort f2h(float f) { _Float16 h = (_Float16)f; return __builtin_bit_cast(ushort, h); }
DEV float  h2f(ushort u) { return (float)__builtin_bit_cast(_Float16, u); }
DEV uint pk2h(float a, float b) {
  return __builtin_bit_cast(uint, __builtin_amdgcn_cvt_pkrtz(a, b));
}

DEV f32x4 MFMA(half8 a, half8 b, f32x4 c) {
  return __builtin_amdgcn_mfma_f32_16x16x32_f16(a, b, c, 0, 0, 0);
}

DEV void async_cp16(void* lds, const void* g) {
  __builtin_amdgcn_global_load_lds((const __attribute__((address_space(1))) void*)g,
                                   (__attribute__((address_space(3))) void*)lds,
                                   16, 0, 0);
}

// ---------------- f32 -> fp16 convert ----------------
__global__ __launch_bounds__(256) void cvt(const float* __restrict__ in,
                                           ushort* __restrict__ out, int n4) {
  const int i = blockIdx.x * 256 + threadIdx.x;
  if (i >= n4) return;
  const float4 v = ((const float4*)in)[i];
  ushort4 o;
  o.x = f2h(v.x); o.y = f2h(v.y); o.z = f2h(v.z); o.w = f2h(v.w);
  ((ushort4*)out)[i] = o;
}

// ---- f32 -> fp16 convert with RoPE row permutation (Wq/Wk only) ----
// Row f = h*128+fr; (j,s) = fr<64 ? (fr,0) : (fr-64,1). Permuted row' =
// h*128 + (j>>4)*32 + s*16 + (j&15): pair (j,j+64) lands 16 cols apart
// within a 32-col group -> same lane, adjacent nf frags in GEMM epilogue.
__global__ __launch_bounds__(256) void wcvt_rope(const float* __restrict__ in,
                                                 ushort* __restrict__ out) {
  const int i = blockIdx.x * 256 + threadIdx.x;   // vec4 idx, 2048*512 total
  const int row = i >> 9, cidx = i & 511;
  const int h = row >> 7, fr = row & 127;
  const int s_ = fr >> 6, j = fr & 63;
  const int rowp = h * 128 + (j >> 4) * 32 + s_ * 16 + (j & 15);
  const float4 v = ((const float4*)in)[i];
  ushort4 o;
  o.x = f2h(v.x); o.y = f2h(v.y); o.z = f2h(v.z); o.w = f2h(v.w);
  ((ushort4*)(out))[rowp * 512 + cidx] = o;
}

// ---------------- fused QKV GEMM 256x256, BK=32, 4-slot ring --------------
// One dispatch, 768 blocks: bn 0..23 spans [Wq;Wk;Wv] (contiguous rows);
// output matrix select = bn>>3 into contiguous Qr/Kr/Vr. Same single-barrier
// counted-vmcnt pipeline as gemm256. For bn<16 (Q,K): RoPE fused in epilogue
// on the permuted feature pairs (acc[mf][2p], acc[mf][2p+1]) — same lane,
// t = m&2047, j = ((wn&1)*2+p)*16+q16, tables L2-resident.
__global__ __launch_bounds__(512, 2) void gemmqkv(const ushort* __restrict__ A,
                                                  const ushort* __restrict__ Bw,
                                                  ushort* __restrict__ Cq,
                                                  const float* __restrict__ cs,
                                                  const float* __restrict__ sn) {
  __shared__ ushort As[4][256 * 32];
  __shared__ ushort Bs[4][256 * 32];
  const int tid = threadIdx.x;                 // 0..511
  const int lane = tid & 63, wid = tid >> 6;   // 8 waves
  const int g = lane >> 4, q16 = lane & 15;
  const int wm = wid >> 2, wn = wid & 3;       // 2M x 4N

  const int flat = (int)blockIdx.x;            // 0..767
  const int xcd = flat & 7, idx = flat >> 3;   // idx 0..95
  const int bm = xcd * 4 + (idx & 3);          // 4 bm-panels per XCD
  const int bn = idx >> 2;                     // 0..23
  const ushort* Ab = A + (size_t)bm * 256 * Dc;
  const ushort* Bb = Bw + (size_t)bn * 256 * Dc;

#define STAGE1(KT, BUF, PH) do {                                               \
    const int pass_ = (PH) & 1;                                                \
    const int c_ = pass_ * 512 + tid;                                          \
    const int row_ = c_ >> 2, gl_ = c_ & 3;                                    \
    const int col_ = (KT) * 32 + ((gl_ ^ ((row_ >> 1) & 3)) << 3);             \
    if ((PH) < 2)                                                              \
      async_cp16(&As[BUF][(pass_ * 512 + wid * 64) * 8],                       \
                 Ab + (size_t)row_ * Dc + col_);                               \
    else                                                                       \
      async_cp16(&Bs[BUF][(pass_ * 512 + wid * 64) * 8],                       \
                 Bb + (size_t)row_ * Dc + col_);                               \
  } while (0)

  f32x4 acc[8][4] = {};

  for (int tt = 0; tt < 3; ++tt) {
    STAGE1(tt, tt, 0); STAGE1(tt, tt, 1);
    STAGE1(tt, tt, 2); STAGE1(tt, tt, 3);
  }

  const int sgz = (g ^ ((q16 >> 1) & 3)) << 3;

#pragma unroll 1
  for (int t = 0; t < 64; ++t) {
    const int rb = t & 3;
    const int sb = (t + 3) & 3;
    const bool st = (t + 3) < 64;
    const ushort* Asb = As[rb];
    const ushort* Bsb = Bs[rb];

    if (t + 2 < 64)      asm volatile("s_waitcnt vmcnt(8)" ::: "memory");
    else if (t + 1 < 64) asm volatile("s_waitcnt vmcnt(4)" ::: "memory");
    else                 asm volatile("s_waitcnt vmcnt(0)" ::: "memory");
    __builtin_amdgcn_s_barrier();
    __builtin_amdgcn_sched_barrier(0);

    half8 af0[4], af1[4], bf[4];
#pragma unroll
    for (int nf = 0; nf < 4; ++nf) {
      const int r = wn * 64 + nf * 16 + q16;
      bf[nf] = *(const half8*)&Bsb[r * 32 + sgz];
    }
#pragma unroll
    for (int mf = 0; mf < 4; ++mf) {
      const int r = wm * 128 + mf * 16 + q16;
      af0[mf] = *(const half8*)&Asb[r * 32 + sgz];
    }
#pragma unroll
    for (int mf = 0; mf < 4; ++mf) {
      const int r = wm * 128 + 64 + mf * 16 + q16;
      af1[mf] = *(const half8*)&Asb[r * 32 + sgz];
    }
    if (st) { STAGE1(t + 3, sb, 0); STAGE1(t + 3, sb, 1);
              STAGE1(t + 3, sb, 2); STAGE1(t + 3, sb, 3); }

    __builtin_amdgcn_s_setprio(1);
#pragma unroll
    for (int mf = 0; mf < 4; ++mf)
#pragma unroll
      for (int nf = 0; nf < 4; ++nf)
        acc[mf][nf] = MFMA(af0[mf], bf[nf], acc[mf][nf]);
#pragma unroll
    for (int mf = 0; mf < 4; ++mf)
#pragma unroll
      for (int nf = 0; nf < 4; ++nf)
        acc[4 + mf][nf] = MFMA(af1[mf], bf[nf], acc[4 + mf][nf]);
    __builtin_amdgcn_s_setprio(0);
  }
#undef STAGE1

  ushort* C = Cq + (size_t)(bn >> 3) * ((size_t)8192 * Dc);
  const int bn8 = bn & 7;
  const int m00 = bm * 256 + wm * 128 + g * 4;
  const int n0 = bn8 * 256 + wn * 64 + q16;

  if (bn < 16) {
    // RoPE epilogue on permuted pairs: lo = acc[mf][2p], hi = acc[mf][2p+1]
#pragma unroll
    for (int mf = 0; mf < 8; ++mf)
#pragma unroll
      for (int p = 0; p < 2; ++p) {
        const int j = ((wn & 1) * 2 + p) * 16 + q16;
#pragma unroll
        for (int r = 0; r < 4; ++r) {
          const int m = m00 + mf * 16 + r;
          const int t = m & (Tc - 1);
          const float c = cs[t * 128 + j];
          const float s_ = sn[t * 128 + j];
          const float lo = acc[mf][2 * p][r];
          const float hi = acc[mf][2 * p + 1][r];
          C[(size_t)m * Dc + n0 + (2 * p) * 16] = f2h(lo * c - hi * s_);
          C[(size_t)m * Dc + n0 + (2 * p + 1) * 16] = f2h(hi * c + lo * s_);
        }
      }
  } else {
#pragma unroll
    for (int mf = 0; mf < 8; ++mf)
#pragma unroll
      for (int nf = 0; nf < 4; ++nf) {
        const int m0 = m00 + mf * 16;
        const int n = n0 + nf * 16;
#pragma unroll
        for (int r = 0; r < 4; ++r)
          C[(size_t)(m0 + r) * Dc + n] = f2h(acc[mf][nf][r]);
      }
  }
}

// ---------------- GEMM 256x256 (final projection, f32 out) ----------------
template <typename OutT>
__global__ __launch_bounds__(512, 2) void gemm256(const ushort* __restrict__ A,
                                                  const ushort* __restrict__ Bw,
                                                  OutT* __restrict__ C) {
  __shared__ ushort As[4][256 * 32];
  __shared__ ushort Bs[4][256 * 32];
  const int tid = threadIdx.x;
  const int lane = tid & 63, wid = tid >> 6;
  const int g = lane >> 4, q16 = lane & 15;
  const int wm = wid >> 2, wn = wid & 3;

  const int flat = (int)blockIdx.x;            // 0..255
  const int xcd = flat & 7, idx = flat >> 3;
  const int bm = xcd * 4 + (idx & 3);
  const int bn = idx >> 2;
  const ushort* Ab = A + (size_t)bm * 256 * Dc;
  const ushort* Bb = Bw + (size_t)bn * 256 * Dc;

#define STAGE1(KT, BUF, PH) do {                                               \
    const int pass_ = (PH) & 1;                                                \
    const int c_ = pass_ * 512 + tid;                                          \
    const int row_ = c_ >> 2, gl_ = c_ & 3;                                    \
    const int col_ = (KT) * 32 + ((gl_ ^ ((row_ >> 1) & 3)) << 3);             \
    if ((PH) < 2)                                                              \
      async_cp16(&As[BUF][(pass_ * 512 + wid * 64) * 8],                       \
                 Ab + (size_t)row_ * Dc + col_);                               \
    else                                                                       \
      async_cp16(&Bs[BUF][(pass_ * 512 + wid * 64) * 8],                       \
                 Bb + (size_t)row_ * Dc + col_);                               \
  } while (0)

  f32x4 acc[8][4] = {};

  for (int tt = 0; tt < 3; ++tt) {
    STAGE1(tt, tt, 0); STAGE1(tt, tt, 1);
    STAGE1(tt, tt, 2); STAGE1(tt, tt, 3);
  }

  const int sgz = (g ^ ((q16 >> 1) & 3)) << 3;

#pragma unroll 1
  for (int t = 0; t < 64; ++t) {
    const int rb = t & 3;
    const int sb = (t + 3) & 3;
    const bool st = (t + 3) < 64;
    const ushort* Asb = As[rb];
    const ushort* Bsb = Bs[rb];

    if (t + 2 < 64)      asm volatile("s_waitcnt vmcnt(8)" ::: "memory");
    else if (t + 1 < 64) asm volatile("s_waitcnt vmcnt(4)" ::: "memory");
    else                 asm volatile("s_waitcnt vmcnt(0)" ::: "memory");
    __builtin_amdgcn_s_barrier();
    __builtin_amdgcn_sched_barrier(0);

    half8 af0[4], af1[4], bf[4];
#pragma unroll
    for (int nf = 0; nf < 4; ++nf) {
      const int r = wn * 64 + nf * 16 + q16;
      bf[nf] = *(const half8*)&Bsb[r * 32 + sgz];
    }
#pragma unroll
    for (int mf = 0; mf < 4; ++mf) {
      const int r = wm * 128 + mf * 16 + q16;
      af0[mf] = *(const half8*)&Asb[r * 32 + sgz];
    }
#pragma unroll
    for (int mf = 0; mf < 4; ++mf) {
      const int r = wm * 128 + 64 + mf * 16 + q16;
      af1[mf] = *(const half8*)&Asb[r * 32 + sgz];
    }
    if (st) { STAGE1(t + 3, sb, 0); STAGE1(t + 3, sb, 1);
              STAGE1(t + 3, sb, 2); STAGE1(t + 3, sb, 3); }

    __builtin_amdgcn_s_setprio(1);
#pragma unroll
    for (int mf = 0; mf < 4; ++mf)
#pragma unroll
      for (int nf = 0; nf < 4; ++nf)
        acc[mf][nf] = MFMA(af0[mf], bf[nf], acc[mf][nf]);
#pragma unroll
    for (int mf = 0; mf < 4; ++mf)
#pragma unroll
      for (int nf = 0; nf < 4; ++nf)
        acc[4 + mf][nf] = MFMA(af1[mf], bf[nf], acc[4 + mf][nf]);
    __builtin_amdgcn_s_setprio(0);
  }
#undef STAGE1

  const int m00 = bm * 256 + wm * 128 + g * 4;
  const int n0 = bn * 256 + wn * 64 + q16;
#pragma unroll
  for (int mf = 0; mf < 8; ++mf)
#pragma unroll
    for (int nf = 0; nf < 4; ++nf) {
      const int m0 = m00 + mf * 16;
      const int n = n0 + nf * 16;
#pragma unroll
      for (int r = 0; r < 4; ++r) {
        const float v = acc[mf][nf][r];
        if constexpr (sizeof(OutT) == 2)
          C[(size_t)(m0 + r) * Dc + n] = (OutT)f2h(v);
        else
          C[(size_t)(m0 + r) * Dc + n] = (OutT)v;
      }
    }
}

// ---------------- causal flash attention (2 q-chains / wave) ----------------
// Round-12 version (known-good 162us). Q/K arrive feature-PERMUTED (shared
// permutation -> QK^T invariant); V in true order. grid (4,64) = 256 blocks,
// 512 threads: 8 waves x 32 q-rows = 256-row supertile, paired {7-p, p}.
__global__ __launch_bounds__(512, 2) void attn(const ushort* __restrict__ Q,
                                               const ushort* __restrict__ K,
                                               const ushort* __restrict__ V,
                                               ushort* __restrict__ O) {
  __shared__ ushort Ks[2][64 * 128];   // [kv][d], XOR-swizzled (granule ^= kv&7)
  __shared__ ushort Vt[2][128 * 64];   // [d][kv], XOR-swizzled rows

  const int tid = threadIdx.x;         // 0..511
  const int lane = tid & 63, wid = tid >> 6;   // wid 0..7
  const int g = lane >> 4, q16 = lane & 15;

  const int flat = (int)(blockIdx.x + 4 * blockIdx.y);    // 0..255
  const int xcd = flat & 7, idx = flat >> 3;              // idx 0..31
  const int bh = xcd + 8 * (idx & 7);                     // head-slot 0..63
  const int pr = idx >> 3;                                // supertile pair 0..3

  const int b = bh >> 4, h = bh & 15;
  const size_t headbase = ((size_t)b * Tc * Hc + h) * 128;  // t-stride = 2048
  const float SCL2 = 0.12751743f;      // log2(e)/sqrt(128)

  const int vdc = (wid & 3) * 4 + (lane & 3);         // 0..15: d = vdc*8..+7
  const int vkvp = (wid >> 2) * 16 + (lane >> 2);     // 0..31: kv pair

  uint4 vreg[2];

#define ISSUEK(KT, BUF) do {                                                   \
    const ushort* Kb_ = K + headbase + (size_t)(KT) * 64 * Dc;                 \
    _Pragma("unroll") for (int i_ = 0; i_ < 2; ++i_) {                         \
      const int c_ = i_ * 512 + tid;                                           \
      const int kv_ = c_ >> 4, gl_ = c_ & 15;                                  \
      async_cp16(&Ks[BUF][(i_ * 512 + wid * 64) * 8],                          \
                 Kb_ + (size_t)kv_ * Dc + ((gl_ ^ (kv_ & 7)) << 3));           \
    }                                                                          \
  } while (0)

#define LOADV(KT) do {                                                         \
    const ushort* p0_ = V + headbase + (size_t)((KT) * 64 + 2 * vkvp) * Dc +   \
                        vdc * 8;                                               \
    vreg[0] = *(const uint4*)p0_;                                              \
    vreg[1] = *(const uint4*)(p0_ + Dc);                                       \
  } while (0)

#define WRITEV(BUF) do {                                                       \
    const ushort* e0_ = (const ushort*)&vreg[0];                               \
    const ushort* e1_ = (const ushort*)&vreg[1];                               \
    _Pragma("unroll") for (int j_ = 0; j_ < 8; ++j_) {                         \
      const int d_ = vdc * 8 + j_;                                             \
      const unsigned w_ = (unsigned)e0_[j_] | ((unsigned)e1_[j_] << 16);       \
      *(unsigned*)&Vt[BUF][(d_ * 64 + 2 * vkvp) ^ ((d_ & 7) << 3)] = w_;       \
    }                                                                          \
  } while (0)

#pragma unroll 1
  for (int half = 0; half < 2; ++half) {
    const int q0 = (half ? pr : 7 - pr) * 256;
    const int qrow = q0 + wid * 32;          // wave owns rows qrow..qrow+31
    const int nt = q0 / 64 + 4;

    half8 qreg[2][4];
#pragma unroll
    for (int qf = 0; qf < 2; ++qf)
#pragma unroll
      for (int ds = 0; ds < 4; ++ds)
        qreg[qf][ds] = *(const half8*)(Q + headbase +
                       (size_t)(qrow + qf * 16 + q16) * Dc + ds * 32 + g * 8);

    f32x4 oacc[2][8] = {};             // O^T frags: row=d (g*4+r), col=q
    float m_[2] = {-1e30f, -1e30f};
    float l_[2] = {0.f, 0.f};          // per-lane partials

    __builtin_amdgcn_s_barrier();      // prior half done reading all LDS bufs
    __builtin_amdgcn_sched_barrier(0);
    ISSUEK(0, 0);
    LOADV(0);
    WRITEV(0);                         // compiler waits vmcnt for vreg here

#pragma unroll 1
    for (int kt = 0; kt < nt; ++kt) {
      const int cur = kt & 1;
      const int kv0 = kt * 64;
      asm volatile("s_waitcnt vmcnt(0) lgkmcnt(0)" ::: "memory");
      __builtin_amdgcn_s_barrier();
      __builtin_amdgcn_sched_barrier(0);
      if (kt + 1 < nt) {
        ISSUEK(kt + 1, cur ^ 1);
        LOADV(kt + 1);
      }

      if (kv0 <= qrow + 31) {          // wave-uniform
        const ushort* Ksb = Ks[cur];
        const ushort* Vtb = Vt[cur];
        f32x4 s[2][4] = {};
        __builtin_amdgcn_s_setprio(1);
#pragma unroll
        for (int ds = 0; ds < 4; ++ds) {
          half8 kf[4];
#pragma unroll
          for (int kvf = 0; kvf < 4; ++kvf) {
            const int kv = kvf * 16 + q16;
            kf[kvf] = *(const half8*)&Ksb[(kv * 128 + ds * 32 + g * 8) ^ ((kv & 7) << 3)];
          }
#pragma unroll
          for (int kvf = 0; kvf < 4; ++kvf)
#pragma unroll
            for (int qf = 0; qf < 2; ++qf)
              s[qf][kvf] = MFMA(kf[kvf], qreg[qf][ds], s[qf][kvf]);
        }
        __builtin_amdgcn_s_setprio(0);
        float pmax[2] = {-1e30f, -1e30f};
        if (kv0 + 63 > qrow) {
#pragma unroll
          for (int qf = 0; qf < 2; ++qf) {
            const int qg = qrow + qf * 16 + q16;
#pragma unroll
            for (int kvf = 0; kvf < 4; ++kvf)
#pragma unroll
              for (int r = 0; r < 4; ++r) {
                float v = s[qf][kvf][r];
                if ((kv0 + kvf * 16 + g * 4 + r) > qg) v = -1e30f;
                s[qf][kvf][r] = v;
                pmax[qf] = fmaxf(pmax[qf], v);
              }
          }
        } else {
#pragma unroll
          for (int qf = 0; qf < 2; ++qf)
#pragma unroll
            for (int kvf = 0; kvf < 4; ++kvf)
#pragma unroll
              for (int r = 0; r < 4; ++r)
                pmax[qf] = fmaxf(pmax[qf], s[qf][kvf][r]);
        }
#pragma unroll
        for (int qf = 0; qf < 2; ++qf) {
          pmax[qf] = fmaxf(pmax[qf], __shfl_xor(pmax[qf], 16));
          pmax[qf] = fmaxf(pmax[qf], __shfl_xor(pmax[qf], 32));
        }
        if (!__all((pmax[0] <= m_[0] + 16.f) & (pmax[1] <= m_[1] + 16.f))) {
#pragma unroll
          for (int qf = 0; qf < 2; ++qf) {
            const float mn2 = fmaxf(m_[qf], pmax[qf]);
            const float alpha = __builtin_exp2f((m_[qf] - mn2) * SCL2);
            m_[qf] = mn2;
            l_[qf] *= alpha;
#pragma unroll
            for (int df = 0; df < 8; ++df)
              oacc[qf][df] *= alpha;
          }
        }
        uint w[2][4][2];
#pragma unroll
        for (int qf = 0; qf < 2; ++qf) {
          const float mn = m_[qf];
          float lsum = 0.f;
#pragma unroll
          for (int kvf = 0; kvf < 4; ++kvf) {
            const float p0 = __builtin_exp2f((s[qf][kvf][0] - mn) * SCL2);
            const float p1 = __builtin_exp2f((s[qf][kvf][1] - mn) * SCL2);
            const float p2 = __builtin_exp2f((s[qf][kvf][2] - mn) * SCL2);
            const float p3 = __builtin_exp2f((s[qf][kvf][3] - mn) * SCL2);
            lsum += (p0 + p1) + (p2 + p3);
            w[qf][kvf][0] = pk2h(p0, p1);
            w[qf][kvf][1] = pk2h(p2, p3);
          }
          l_[qf] += lsum;
        }
        const bool ghi = g >= 2;
        const bool godd = (g & 1) != 0;
        half8 pb[2][2];
#pragma unroll
        for (int qf = 0; qf < 2; ++qf) {
          uint sA[2][2], sB[2][2];
#pragma unroll
          for (int c = 0; c < 2; ++c)
#pragma unroll
            for (int i = 0; i < 2; ++i) {
              sA[c][i] = ghi ? w[qf][2 * c + 1][i] : w[qf][2 * c][i];
              sB[c][i] = ghi ? w[qf][2 * c][i] : w[qf][2 * c + 1][i];
            }
          uint x16[2][2], x32[2][2], x48[2][2];
#pragma unroll
          for (int c = 0; c < 2; ++c)
#pragma unroll
            for (int i = 0; i < 2; ++i) {
              x16[c][i] = __shfl_xor(sA[c][i], 16);
              x32[c][i] = __shfl_xor(sB[c][i], 32);
              x48[c][i] = __shfl_xor(sB[c][i], 48);
            }
#pragma unroll
          for (int c = 0; c < 2; ++c) {
            uint4 t;
            t.x = godd ? (ghi ? x16[c][0] : x48[c][0]) : (ghi ? x32[c][0] : sA[c][0]);
            t.y = godd ? (ghi ? x16[c][1] : x48[c][1]) : (ghi ? x32[c][1] : sA[c][1]);
            t.z = godd ? (ghi ? sA[c][0] : x32[c][0]) : (ghi ? x48[c][0] : x16[c][0]);
            t.w = godd ? (ghi ? sA[c][1] : x32[c][1]) : (ghi ? x48[c][1] : x16[c][1]);
            pb[qf][c] = __builtin_bit_cast(half8, t);
          }
        }
        __builtin_amdgcn_s_setprio(1);
#pragma unroll
        for (int c = 0; c < 2; ++c) {
#pragma unroll
          for (int df = 0; df < 8; ++df) {
            const int d = df * 16 + q16;
            const half8 vf = *(const half8*)&Vtb[(d * 64 + c * 32 + g * 8) ^ ((d & 7) << 3)];
#pragma unroll
            for (int qf = 0; qf < 2; ++qf)
              oacc[qf][df] = MFMA(vf, pb[qf][c], oacc[qf][df]);
          }
        }
        __builtin_amdgcn_s_setprio(0);
      }

      if (kt + 1 < nt) WRITEV(cur ^ 1);
    }

#pragma unroll
    for (int qf = 0; qf < 2; ++qf) {
      float l = l_[qf];
      l += __shfl_xor(l, 16);
      l += __shfl_xor(l, 32);
      const float inv = 1.0f / l;
      const int t = qrow + qf * 16 + q16;
#pragma unroll
      for (int df = 0; df < 8; ++df) {
        const f32x4 v = oacc[qf][df];
        ushort4 o;
        o.x = f2h(v[0] * inv); o.y = f2h(v[1] * inv);
        o.z = f2h(v[2] * inv); o.w = f2h(v[3] * inv);
        *(ushort4*)(O + headbase + (size_t)t * Dc + df * 16 + g * 4) = o;
      }
    }
  }
#undef ISSUEK
#undef LOADV
#undef WRITEV
}

extern "C" void kernel_launch(void* const* d_in, const int* in_sizes, int n_in,
                              void* d_out, int out_size, void* d_ws, size_t ws_size,
                              hipStream_t stream) {
  (void)in_sizes; (void)n_in; (void)out_size; (void)ws_size;
  const float* x  = (const float*)d_in[0];
  const float* cs = (const float*)d_in[1];
  const float* sn = (const float*)d_in[2];
  // d_in[3] = mask (unused: causal handled analytically)
  const float* Wq = (const float*)d_in[4];
  const float* Wk = (const float*)d_in[5];
  const float* Wv = (const float*)d_in[6];
  const float* Wo = (const float*)d_in[7];
  float* out = (float*)d_out;

  char* ws = (char*)d_ws;
  const size_t MB = 1024 * 1024;
  ushort* xb  = (ushort*)(ws);            // 32MB x fp16; reused as attn output O
  ushort* wqb = (ushort*)(ws + 32 * MB);  // wq,wk,wv CONTIGUOUS = [6144][2048]
  ushort* wkb = (ushort*)(ws + 40 * MB);
  ushort* wvb = (ushort*)(ws + 48 * MB);
  ushort* wob = (ushort*)(ws + 56 * MB);
  ushort* Qr  = (ushort*)(ws + 64 * MB);  // Qr,Kr,Vr CONTIGUOUS 32MB each
  ushort* Kr  = (ushort*)(ws + 96 * MB);
  ushort* Vr  = (ushort*)(ws + 128 * MB); // end: 160MB

  cvt<<<16384, 256, 0, stream>>>(x, xb, 4194304);
  wcvt_rope<<<4096, 256, 0, stream>>>(Wq, wqb);   // row-permuted for fused RoPE
  wcvt_rope<<<4096, 256, 0, stream>>>(Wk, wkb);
  cvt<<<4096, 256, 0, stream>>>(Wv, wvb, 1048576);
  cvt<<<4096, 256, 0, stream>>>(Wo, wob, 1048576);

  gemmqkv<<<768, 512, 0, stream>>>(xb, wqb, Qr, cs, sn);

  attn<<<dim3(4, 64), 512, 0, stream>>>(Qr, Kr, Vr, xb);

  gemm256<float><<<256, 512, 0, stream>>>(xb, wob, out);
}